// Round 5
// baseline (173.768 us; speedup 1.0000x reference)
//
#include <hip/hip_runtime.h>
#include <stdint.h>

// Problem constants (match reference)
#define HH 512
#define WW 512
#define CC 3
#define KK 32
#define SS 4
#define PP 10
#define NPATCH 126            // (512 + 20 - 32)/4 + 1
#define NP2 (NPATCH * NPATCH) // 15876
#define DD 3072               // C*K*K
#define NMEM 4096
#define THRESHV 0.5f

// ws layout (32-bit words). HARDENING RULE (R4 post-mortem): every word read
// by any kernel is UNCONDITIONALLY written by an earlier kernel, and no
// single-word flag gates conditional writes that are later read. All gates
// are bulk arrays written by every owning block on every launch.
#define OFF_NORMS  0        // 4096 f:  per-row ||m||^2        (fused_main)
#define OFF_PNORM  4096     // 15876 f: per-patch ||u||^2      (fused_main)
#define OFF_MODCNT 20480    // 64 u32:  per-block #patches fixed (cert_fix)
#define OFF_PMAXA  36864    // 1024 f:  per-block fold max     (fused_main)
#define OFF_PMAXB  37888    // 1024 f:  final per-block max    (rescan_pmax)

__device__ inline float wave_max(float v) {
    for (int off = 32; off; off >>= 1) v = fmaxf(v, __shfl_xor(v, off, 64));
    return v;
}
__device__ inline float wave_min(float v) {
    for (int off = 32; off; off >>= 1) v = fminf(v, __shfl_xor(v, off, 64));
    return v;
}
__device__ inline float wave_sum(float v) {
    for (int off = 32; off; off >>= 1) v += __shfl_xor(v, off, 64);
    return v;
}

// Coverage count along one axis: # patch positions i with i*S <= v+P <= i*S+K-1
__device__ inline int cov1(int v) {
    int pv = v + PP;
    int a = pv - (KK - 1);
    int imin = (a <= 0) ? 0 : ((a + SS - 1) >> 2);
    int imax = pv >> 2;
    if (imax > NPATCH - 1) imax = NPATCH - 1;
    return imax - imin + 1;
}

// Kernel 1 (1152 blocks x 256):
//  blocks 0..1023  : mem row norms (4 rows/block, 12x float4 unrolled) +
//                    certified fold (out = img * cov_y * cov_x) + pmaxA.
//  blocks 1024..1149: per-patch ||u||^2 for patch-row py=b-1024 via separable
//                    column window-sums (hides under the 51 MB HBM read).
__global__ void fused_main(const float* __restrict__ mem,
                           const float* __restrict__ img,
                           float* __restrict__ norms,
                           float* __restrict__ pnorm,
                           float* __restrict__ pmaxA,
                           float* __restrict__ out) {
    __shared__ float cs[WW];   // patch path: column sums
    __shared__ float smx[4];   // norm path: per-wave maxes
    int b = blockIdx.x, tid = threadIdx.x;
    int lane = tid & 63, w = tid >> 6;

    if (b >= 1024) {
        int py = b - 1024;
        if (py >= NPATCH) return;
        int y0 = py * SS - PP;
        float s0 = 0.f, s1 = 0.f;
        int x0c = tid, x1c = tid + 256;
#pragma unroll
        for (int ky = 0; ky < KK; ++ky) {
            int y = y0 + ky;
            if (y >= 0 && y < HH) {
                const float* row = img + (size_t)y * WW * CC;
                const float* p0 = row + x0c * CC;
                const float* p1 = row + x1c * CC;
                s0 += p0[0] * p0[0] + p0[1] * p0[1] + p0[2] * p0[2];
                s1 += p1[0] * p1[0] + p1[1] * p1[1] + p1[2] * p1[2];
            }
        }
        cs[x0c] = s0;
        cs[x1c] = s1;
        __syncthreads();
        if (tid < NPATCH) {
            int x0 = tid * SS - PP;
            float t = 0.f;
#pragma unroll
            for (int kx = 0; kx < KK; ++kx) {
                int xx = x0 + kx;
                if (xx >= 0 && xx < WW) t += cs[xx];
            }
            pnorm[py * NPATCH + tid] = t;
        }
        return;
    }

    // ---- fold part (threads 0..191; 1024*192 float4 == H*W*C/4) ----
    float m = -INFINITY;
    if (tid < 192) {
        int f = b * 192 + tid;
        float4 v = ((const float4*)img)[f];
        float r[4] = {v.x, v.y, v.z, v.w};
        int e = f * 4;
#pragma unroll
        for (int k = 0; k < 4; ++k) {
            int px = (e + k) / 3;
            int y = px >> 9, x = px & 511;
            float cv = (float)(cov1(y) * cov1(x));
            r[k] *= cv;
            m = fmaxf(m, r[k]);
        }
        float4 o; o.x = r[0]; o.y = r[1]; o.z = r[2]; o.w = r[3];
        ((float4*)out)[f] = o;
    }

    // ---- mem norms (all 4 waves, one row each) ----
    int row = b * 4 + w;
    const float4* rp = (const float4*)(mem + (size_t)row * DD); // 768 f4/row
    float4 v[12];
#pragma unroll
    for (int i = 0; i < 12; ++i) v[i] = rp[lane + (i << 6)];
    float s0 = 0.f, s1 = 0.f, s2 = 0.f, s3 = 0.f;
#pragma unroll
    for (int i = 0; i < 12; ++i) {
        s0 += v[i].x * v[i].x; s1 += v[i].y * v[i].y;
        s2 += v[i].z * v[i].z; s3 += v[i].w * v[i].w;
    }
    float s = wave_sum((s0 + s1) + (s2 + s3));
    if (lane == 0) norms[row] = s;

    // ---- block max -> pmaxA[b] ----
    m = wave_max(m);
    if (lane == 0) smx[w] = m;
    __syncthreads();
    if (tid == 0)
        pmaxA[b] = fmaxf(fmaxf(smx[0], smx[1]), fmaxf(smx[2], smx[3]));
}

// Kernel 2 (64 blocks x 256): certification + exact fallback, fused.
// Each block: (a) redundant min/max reduce of the 4096 mem norms (L2-hot),
// (b) reverse-triangle bound  d2 >= (||m||-||u||)^2  for its slice of the
// 15876 patches, (c) full distance argmin + output fix for any uncertified
// patch (normally none), (d) UNCONDITIONAL write of modcnt[block].
__global__ void cert_fix(const float* __restrict__ img,
                         const float* __restrict__ mem,
                         const float* __restrict__ mem2,
                         const int* __restrict__ mapping,
                         const float* __restrict__ norms,
                         const float* __restrict__ pnorm,
                         float* __restrict__ out,
                         uint32_t* __restrict__ modcnt) {
    __shared__ float rmn[4], rmx[4];
    __shared__ float s_mn, s_mx;
    __shared__ float smin[256];
    __shared__ int   sarg[256];
    __shared__ int   s_mod;
    int tid = threadIdx.x, lane = tid & 63, w = tid >> 6;
    if (tid == 0) s_mod = 0;

    // (a) min/max of mem norms (4096 / 256 = 16 per thread)
    float mn = INFINITY, mx = -INFINITY;
#pragma unroll
    for (int k = 0; k < 16; ++k) {
        float v = norms[tid + (k << 8)];
        mn = fminf(mn, v); mx = fmaxf(mx, v);
    }
    mn = wave_min(mn); mx = wave_max(mx);
    if (lane == 0) { rmn[w] = mn; rmx[w] = mx; }
    __syncthreads();
    if (tid == 0) {
        s_mn = sqrtf(fminf(fminf(rmn[0], rmn[1]), fminf(rmn[2], rmn[3])));
        s_mx = sqrtf(fmaxf(fmaxf(rmx[0], rmx[1]), fmaxf(rmx[2], rmx[3])));
    }
    __syncthreads();
    float lo = s_mn, hi = s_mx;

    // (b)+(c) this block's patch slice
    int per = (NP2 + gridDim.x - 1) / gridDim.x;
    int p0 = blockIdx.x * per;
    int p1 = p0 + per; if (p1 > NP2) p1 = NP2;
    for (int p = p0; p < p1; ++p) {
        float un = sqrtf(pnorm[p]);   // same address all threads: broadcast
        float gap = 0.f;
        if (un <= lo) gap = lo - un;
        else if (un >= hi) gap = un - hi;
        if (gap * gap >= THRESHV) continue;   // certified; block-uniform

        // exact path (block-uniform branch; barriers safe)
        int pi = p / NPATCH, pj = p % NPATCH;
        int y0 = pi * SS - PP, x0 = pj * SS - PP;
        float best = INFINITY; int barg = NMEM;
        for (int j = tid; j < NMEM; j += 256) {
            const float* mr = mem + (size_t)j * DD;
            float sacc = 0.f;
            for (int d = 0; d < DD; ++d) {
                int c = d >> 10, rem = d & 1023, ky = rem >> 5, kx = rem & 31;
                int y = y0 + ky, x = x0 + kx;
                float u = (y >= 0 && y < HH && x >= 0 && x < WW)
                              ? img[((size_t)y * WW + x) * CC + c] : 0.f;
                float dif = u - mr[d];
                sacc += dif * dif;
            }
            if (sacc < best) { best = sacc; barg = j; }
        }
        smin[tid] = best; sarg[tid] = barg;
        __syncthreads();
        for (int stride = 128; stride; stride >>= 1) {
            if (tid < stride) {
                float s2 = smin[tid + stride];
                int   a2 = sarg[tid + stride];
                if (s2 < smin[tid] || (s2 == smin[tid] && a2 < sarg[tid])) {
                    smin[tid] = s2; sarg[tid] = a2;
                }
            }
            __syncthreads();
        }
        float dmin = smin[0]; int arg = sarg[0];
        if (dmin < THRESHV) {
            const float* rec = mem2 + (size_t)mapping[arg] * DD;
            for (int d = tid; d < DD; d += 256) {
                int c = d >> 10, rem = d & 1023, ky = rem >> 5, kx = rem & 31;
                int y = y0 + ky, x = x0 + kx;
                if (y >= 0 && y < HH && x >= 0 && x < WW) {
                    float u = img[((size_t)y * WW + x) * CC + c];
                    atomicAdd(&out[((size_t)y * WW + x) * CC + c],
                              rec[d] - u);
                }
            }
            if (tid == 0) s_mod++;
        }
        __syncthreads();
    }
    __syncthreads();
    if (tid == 0) modcnt[blockIdx.x] = (uint32_t)s_mod;  // UNCONDITIONAL
}

// Kernel 3 (1024 blocks x 256): ALWAYS writes pmaxB[b] — copy of pmaxA[b]
// when no patch was modified, else recomputed from the patched output.
__global__ void rescan_pmax(const uint32_t* __restrict__ modcnt,
                            const float* __restrict__ pmaxA,
                            const float* __restrict__ out,
                            float* __restrict__ pmaxB) {
    __shared__ int s_need;
    __shared__ float smx[4];
    int tid = threadIdx.x, lane = tid & 63, w = tid >> 6;
    if (w == 0) {  // first wave sums the 64 counts
        int c = (int)modcnt[lane];
        for (int off = 32; off; off >>= 1) c += __shfl_xor(c, off, 64);
        if (lane == 0) s_need = c;
    }
    __syncthreads();
    if (s_need == 0) {                    // block-uniform
        if (tid == 0) pmaxB[blockIdx.x] = pmaxA[blockIdx.x];
        return;
    }
    float m = -INFINITY;
    if (tid < 192) {
        int f = blockIdx.x * 192 + tid;
        float4 v = ((const float4*)out)[f];
        m = fmaxf(fmaxf(v.x, v.y), fmaxf(v.z, v.w));
    }
    m = wave_max(m);
    if (lane == 0) smx[w] = m;
    __syncthreads();
    if (tid == 0)
        pmaxB[blockIdx.x] = fmaxf(fmaxf(smx[0], smx[1]), fmaxf(smx[2], smx[3]));
}

// Kernel 4 (256 blocks x 256): reduce pmaxB (always valid), divide output.
__global__ void normalize_k(const float* __restrict__ pmaxB,
                            float* __restrict__ out) {
    __shared__ float smx[4];
    __shared__ float s_inv;
    int tid = threadIdx.x, lane = tid & 63, w = tid >> 6;
    float m = -INFINITY;
#pragma unroll
    for (int k = 0; k < 4; ++k) m = fmaxf(m, pmaxB[tid + (k << 8)]);
    m = wave_max(m);
    if (lane == 0) smx[w] = m;
    __syncthreads();
    if (tid == 0)
        s_inv = 1.0f / fmaxf(fmaxf(smx[0], smx[1]), fmaxf(smx[2], smx[3]));
    __syncthreads();
    float inv = s_inv;
    float4* o4 = (float4*)out;
    int base = blockIdx.x * 768 + tid;
#pragma unroll
    for (int k = 0; k < 3; ++k) {
        int f = base + (k << 8);
        float4 v = o4[f];
        v.x *= inv; v.y *= inv; v.z *= inv; v.w *= inv;
        o4[f] = v;
    }
}

extern "C" void kernel_launch(void* const* d_in, const int* in_sizes, int n_in,
                              void* d_out, int out_size, void* d_ws, size_t ws_size,
                              hipStream_t stream) {
    const float* img     = (const float*)d_in[0];
    const float* mem     = (const float*)d_in[1];
    const float* mem2    = (const float*)d_in[2];
    const int*   mapping = (const int*)d_in[3];
    float* out    = (float*)d_out;
    uint32_t* wsu = (uint32_t*)d_ws;

    float*    norms  = (float*)(wsu + OFF_NORMS);
    float*    pnorm  = (float*)(wsu + OFF_PNORM);
    uint32_t* modcnt = wsu + OFF_MODCNT;
    float*    pmaxA  = (float*)(wsu + OFF_PMAXA);
    float*    pmaxB  = (float*)(wsu + OFF_PMAXB);

    fused_main <<<1152, 256, 0, stream>>>(mem, img, norms, pnorm, pmaxA, out);
    cert_fix   <<<64, 256, 0, stream>>>(img, mem, mem2, mapping, norms,
                                        pnorm, out, modcnt);
    rescan_pmax<<<1024, 256, 0, stream>>>(modcnt, pmaxA, out, pmaxB);
    normalize_k<<<256, 256, 0, stream>>>(pmaxB, out);
}

// Round 6
// 130.881 us; speedup vs baseline: 1.3277x; 1.3277x over previous
//
#include <hip/hip_runtime.h>
#include <stdint.h>

// Problem constants (match reference)
#define HH 512
#define WW 512
#define CC 3
#define KK 32
#define SS 4
#define PP 10
#define NPATCH 126            // (512 + 20 - 32)/4 + 1
#define NP2 (NPATCH * NPATCH) // 15876
#define DD 3072               // C*K*K
#define NMEM 4096
#define THRESHV 0.5f

// ws layout (32-bit words). HARDENING RULE (R4 post-mortem): every word read
// by any kernel is UNCONDITIONALLY written by an earlier kernel, and no
// single-word flag gates conditional writes that are later read. All gates
// are bulk arrays written by every owning block on every launch.
#define OFF_NORMS  0        // 4096 f:  per-row ||m||^2        (fused_main)
#define OFF_PNORM  4096     // 15876 f: per-patch ||u||^2      (fused_main)
#define OFF_MODCNT 20480    // 64 u32:  per-block #patches fixed (cert_fix)
#define OFF_PMAXA  36864    // 1024 f:  per-block fold max     (fused_main)
#define OFF_PMAXB  37888    // 1024 f:  final per-block max    (rescan_pmax)

__device__ inline float wave_max(float v) {
    for (int off = 32; off; off >>= 1) v = fmaxf(v, __shfl_xor(v, off, 64));
    return v;
}
__device__ inline float wave_min(float v) {
    for (int off = 32; off; off >>= 1) v = fminf(v, __shfl_xor(v, off, 64));
    return v;
}
__device__ inline float wave_sum(float v) {
    for (int off = 32; off; off >>= 1) v += __shfl_xor(v, off, 64);
    return v;
}

// Coverage count along one axis: # patch positions i with i*S <= v+P <= i*S+K-1
__device__ inline int cov1(int v) {
    int pv = v + PP;
    int a = pv - (KK - 1);
    int imin = (a <= 0) ? 0 : ((a + SS - 1) >> 2);
    int imax = pv >> 2;
    if (imax > NPATCH - 1) imax = NPATCH - 1;
    return imax - imin + 1;
}

// Kernel 1 (1152 blocks x 256):
//  blocks 0..1023  : mem row norms (4 rows/block, 12x float4 unrolled) +
//                    certified fold (out = img * cov_y * cov_x) + pmaxA.
//  blocks 1024..1149: per-patch ||u||^2 for patch-row py=b-1024 via separable
//                    column window-sums (hides under the 51 MB HBM read).
__global__ void fused_main(const float* __restrict__ mem,
                           const float* __restrict__ img,
                           float* __restrict__ norms,
                           float* __restrict__ pnorm,
                           float* __restrict__ pmaxA,
                           float* __restrict__ out) {
    __shared__ float cs[WW];   // patch path: column sums
    __shared__ float smx[4];   // norm path: per-wave maxes
    int b = blockIdx.x, tid = threadIdx.x;
    int lane = tid & 63, w = tid >> 6;

    if (b >= 1024) {
        int py = b - 1024;
        if (py >= NPATCH) return;
        int y0 = py * SS - PP;
        float s0 = 0.f, s1 = 0.f;
        int x0c = tid, x1c = tid + 256;
#pragma unroll
        for (int ky = 0; ky < KK; ++ky) {
            int y = y0 + ky;
            if (y >= 0 && y < HH) {
                const float* row = img + (size_t)y * WW * CC;
                const float* p0 = row + x0c * CC;
                const float* p1 = row + x1c * CC;
                s0 += p0[0] * p0[0] + p0[1] * p0[1] + p0[2] * p0[2];
                s1 += p1[0] * p1[0] + p1[1] * p1[1] + p1[2] * p1[2];
            }
        }
        cs[x0c] = s0;
        cs[x1c] = s1;
        __syncthreads();
        if (tid < NPATCH) {
            int x0 = tid * SS - PP;
            float t = 0.f;
#pragma unroll
            for (int kx = 0; kx < KK; ++kx) {
                int xx = x0 + kx;
                if (xx >= 0 && xx < WW) t += cs[xx];
            }
            pnorm[py * NPATCH + tid] = t;
        }
        return;
    }

    // ---- fold part (threads 0..191; 1024*192 float4 == H*W*C/4) ----
    float m = -INFINITY;
    if (tid < 192) {
        int f = b * 192 + tid;
        float4 v = ((const float4*)img)[f];
        float r[4] = {v.x, v.y, v.z, v.w};
        int e = f * 4;
#pragma unroll
        for (int k = 0; k < 4; ++k) {
            int px = (e + k) / 3;
            int y = px >> 9, x = px & 511;
            float cv = (float)(cov1(y) * cov1(x));
            r[k] *= cv;
            m = fmaxf(m, r[k]);
        }
        float4 o; o.x = r[0]; o.y = r[1]; o.z = r[2]; o.w = r[3];
        ((float4*)out)[f] = o;
    }

    // ---- mem norms (all 4 waves, one row each) ----
    int row = b * 4 + w;
    const float4* rp = (const float4*)(mem + (size_t)row * DD); // 768 f4/row
    float4 v[12];
#pragma unroll
    for (int i = 0; i < 12; ++i) v[i] = rp[lane + (i << 6)];
    float s0 = 0.f, s1 = 0.f, s2 = 0.f, s3 = 0.f;
#pragma unroll
    for (int i = 0; i < 12; ++i) {
        s0 += v[i].x * v[i].x; s1 += v[i].y * v[i].y;
        s2 += v[i].z * v[i].z; s3 += v[i].w * v[i].w;
    }
    float s = wave_sum((s0 + s1) + (s2 + s3));
    if (lane == 0) norms[row] = s;

    // ---- block max -> pmaxA[b] ----
    m = wave_max(m);
    if (lane == 0) smx[w] = m;
    __syncthreads();
    if (tid == 0)
        pmaxA[b] = fmaxf(fmaxf(smx[0], smx[1]), fmaxf(smx[2], smx[3]));
}

// Kernel 2 (64 blocks x 256): certification + exact fallback, fused.
// (a) redundant min/max reduce of the 4096 mem norms (L2-hot, coalesced),
// (b) PARALLEL reverse-triangle bound check of this block's patch slice
//     (thread tid checks p0+tid, p0+tid+256, ... — coalesced pnorm reads),
//     failures pushed to an LDS list (capacity 256 >= slice size 249),
// (c) cooperative exact fix for each listed patch (normally zero),
// (d) UNCONDITIONAL write of modcnt[block].
__global__ void cert_fix(const float* __restrict__ img,
                         const float* __restrict__ mem,
                         const float* __restrict__ mem2,
                         const int* __restrict__ mapping,
                         const float* __restrict__ norms,
                         const float* __restrict__ pnorm,
                         float* __restrict__ out,
                         uint32_t* __restrict__ modcnt) {
    __shared__ float rmn[4], rmx[4];
    __shared__ float s_mn, s_mx;
    __shared__ float smin[256];
    __shared__ int   sarg[256];
    __shared__ uint32_t s_cnt;
    __shared__ uint32_t s_list[256];
    __shared__ int   s_mod;
    int tid = threadIdx.x, lane = tid & 63, w = tid >> 6;
    if (tid == 0) { s_mod = 0; s_cnt = 0; }

    // (a) min/max of mem norms (4096 / 256 = 16 per thread, coalesced)
    float mn = INFINITY, mx = -INFINITY;
#pragma unroll
    for (int k = 0; k < 16; ++k) {
        float v = norms[tid + (k << 8)];
        mn = fminf(mn, v); mx = fmaxf(mx, v);
    }
    mn = wave_min(mn); mx = wave_max(mx);
    if (lane == 0) { rmn[w] = mn; rmx[w] = mx; }
    __syncthreads();
    if (tid == 0) {
        s_mn = sqrtf(fminf(fminf(rmn[0], rmn[1]), fminf(rmn[2], rmn[3])));
        s_mx = sqrtf(fmaxf(fmaxf(rmx[0], rmx[1]), fmaxf(rmx[2], rmx[3])));
    }
    __syncthreads();
    float lo = s_mn, hi = s_mx;

    // (b) parallel bound check of this block's slice
    int per = (NP2 + gridDim.x - 1) / gridDim.x;   // 249 @ 64 blocks
    int p0 = blockIdx.x * per;
    int p1 = p0 + per; if (p1 > NP2) p1 = NP2;
    for (int p = p0 + tid; p < p1; p += 256) {
        float un = sqrtf(pnorm[p]);                 // coalesced
        float gap = 0.f;
        if (un <= lo) gap = lo - un;
        else if (un >= hi) gap = un - hi;
        if (gap * gap < THRESHV) {
            uint32_t pos = atomicAdd(&s_cnt, 1u);   // LDS atomic
            s_list[pos] = (uint32_t)p;
        }
    }
    __syncthreads();
    uint32_t nf = s_cnt;                            // block-uniform

    // (c) cooperative exact fix for each failure (normally nf == 0)
    for (uint32_t e = 0; e < nf; ++e) {
        int p = (int)s_list[e];
        int pi = p / NPATCH, pj = p % NPATCH;
        int y0 = pi * SS - PP, x0 = pj * SS - PP;
        float best = INFINITY; int barg = NMEM;
        for (int j = tid; j < NMEM; j += 256) {
            const float* mr = mem + (size_t)j * DD;
            float sacc = 0.f;
            for (int d = 0; d < DD; ++d) {
                int c = d >> 10, rem = d & 1023, ky = rem >> 5, kx = rem & 31;
                int y = y0 + ky, x = x0 + kx;
                float u = (y >= 0 && y < HH && x >= 0 && x < WW)
                              ? img[((size_t)y * WW + x) * CC + c] : 0.f;
                float dif = u - mr[d];
                sacc += dif * dif;
            }
            if (sacc < best) { best = sacc; barg = j; }
        }
        smin[tid] = best; sarg[tid] = barg;
        __syncthreads();
        for (int stride = 128; stride; stride >>= 1) {
            if (tid < stride) {
                float s2 = smin[tid + stride];
                int   a2 = sarg[tid + stride];
                if (s2 < smin[tid] || (s2 == smin[tid] && a2 < sarg[tid])) {
                    smin[tid] = s2; sarg[tid] = a2;
                }
            }
            __syncthreads();
        }
        float dmin = smin[0]; int arg = sarg[0];
        if (dmin < THRESHV) {
            const float* rec = mem2 + (size_t)mapping[arg] * DD;
            for (int d = tid; d < DD; d += 256) {
                int c = d >> 10, rem = d & 1023, ky = rem >> 5, kx = rem & 31;
                int y = y0 + ky, x = x0 + kx;
                if (y >= 0 && y < HH && x >= 0 && x < WW) {
                    float u = img[((size_t)y * WW + x) * CC + c];
                    atomicAdd(&out[((size_t)y * WW + x) * CC + c],
                              rec[d] - u);
                }
            }
            if (tid == 0) s_mod++;
        }
        __syncthreads();
    }
    if (tid == 0) modcnt[blockIdx.x] = (uint32_t)s_mod;  // UNCONDITIONAL
}

// Kernel 3 (1024 blocks x 256): ALWAYS writes pmaxB[b] — copy of pmaxA[b]
// when no patch was modified, else recomputed from the patched output.
__global__ void rescan_pmax(const uint32_t* __restrict__ modcnt,
                            const float* __restrict__ pmaxA,
                            const float* __restrict__ out,
                            float* __restrict__ pmaxB) {
    __shared__ int s_need;
    __shared__ float smx[4];
    int tid = threadIdx.x, lane = tid & 63, w = tid >> 6;
    if (w == 0) {  // first wave sums the 64 counts
        int c = (int)modcnt[lane];
        for (int off = 32; off; off >>= 1) c += __shfl_xor(c, off, 64);
        if (lane == 0) s_need = c;
    }
    __syncthreads();
    if (s_need == 0) {                    // block-uniform
        if (tid == 0) pmaxB[blockIdx.x] = pmaxA[blockIdx.x];
        return;
    }
    float m = -INFINITY;
    if (tid < 192) {
        int f = blockIdx.x * 192 + tid;
        float4 v = ((const float4*)out)[f];
        m = fmaxf(fmaxf(v.x, v.y), fmaxf(v.z, v.w));
    }
    m = wave_max(m);
    if (lane == 0) smx[w] = m;
    __syncthreads();
    if (tid == 0)
        pmaxB[blockIdx.x] = fmaxf(fmaxf(smx[0], smx[1]), fmaxf(smx[2], smx[3]));
}

// Kernel 4 (256 blocks x 256): reduce pmaxB (always valid), divide output.
__global__ void normalize_k(const float* __restrict__ pmaxB,
                            float* __restrict__ out) {
    __shared__ float smx[4];
    __shared__ float s_inv;
    int tid = threadIdx.x, lane = tid & 63, w = tid >> 6;
    float m = -INFINITY;
#pragma unroll
    for (int k = 0; k < 4; ++k) m = fmaxf(m, pmaxB[tid + (k << 8)]);
    m = wave_max(m);
    if (lane == 0) smx[w] = m;
    __syncthreads();
    if (tid == 0)
        s_inv = 1.0f / fmaxf(fmaxf(smx[0], smx[1]), fmaxf(smx[2], smx[3]));
    __syncthreads();
    float inv = s_inv;
    float4* o4 = (float4*)out;
    int base = blockIdx.x * 768 + tid;
#pragma unroll
    for (int k = 0; k < 3; ++k) {
        int f = base + (k << 8);
        float4 v = o4[f];
        v.x *= inv; v.y *= inv; v.z *= inv; v.w *= inv;
        o4[f] = v;
    }
}

extern "C" void kernel_launch(void* const* d_in, const int* in_sizes, int n_in,
                              void* d_out, int out_size, void* d_ws, size_t ws_size,
                              hipStream_t stream) {
    const float* img     = (const float*)d_in[0];
    const float* mem     = (const float*)d_in[1];
    const float* mem2    = (const float*)d_in[2];
    const int*   mapping = (const int*)d_in[3];
    float* out    = (float*)d_out;
    uint32_t* wsu = (uint32_t*)d_ws;

    float*    norms  = (float*)(wsu + OFF_NORMS);
    float*    pnorm  = (float*)(wsu + OFF_PNORM);
    uint32_t* modcnt = wsu + OFF_MODCNT;
    float*    pmaxA  = (float*)(wsu + OFF_PMAXA);
    float*    pmaxB  = (float*)(wsu + OFF_PMAXB);

    fused_main <<<1152, 256, 0, stream>>>(mem, img, norms, pnorm, pmaxA, out);
    cert_fix   <<<64, 256, 0, stream>>>(img, mem, mem2, mapping, norms,
                                        pnorm, out, modcnt);
    rescan_pmax<<<1024, 256, 0, stream>>>(modcnt, pmaxA, out, pmaxB);
    normalize_k<<<256, 256, 0, stream>>>(pmaxB, out);
}